// Round 16
// baseline (23166.116 us; speedup 1.0000x reference)
//
#include <hip/hip_runtime.h>

typedef unsigned short u16;
typedef unsigned int u32;
typedef unsigned long long u64;

using bf16x8 = __attribute__((ext_vector_type(8))) __bf16;
using f32x4  = __attribute__((ext_vector_type(4))) float;

#define T_DIM 512
#define B_DIM 256
#define E_DIM 512
#define U_DIM 1024
#define K_DIM 1536   /* E+U */
#define NG    2048   /* 2U */
#define NWG   128    /* 128 WGs x 512 thr: 8 waves/CU = 2/SIMD on 128 CUs */

__device__ __forceinline__ u16 f2bf(float f) {
  union { float f; u32 u; } v; v.f = f;
  return (u16)((v.u + 0x7fffu + ((v.u >> 16) & 1u)) >> 16);
}

// ---- device-coherent cross-WG traffic (r14-proven).
// h/rh transposed layout hT[row/16][k/8][row%16][8] (u16):
//   elem_addr = (row>>4)*16384 + (k>>3)*128 + (row&15)*8 + (k&7)
// One wave load instruction covers 1024 contiguous B = 8 lines.
#define WAIT_VM_ALL() do { asm volatile("s_waitcnt vmcnt(0)" ::: "memory"); \
                           __builtin_amdgcn_sched_barrier(0); } while (0)

#define LD16T(dst, base, OFS) \
  asm volatile("global_load_dwordx4 %0, %1, off offset:" #OFS " sc0 sc1" \
               : "=&v"(dst) : "v"(base))

#define LOAD32T(arr, b) do { \
  const u16* _b0 = (b);           const u16* _b1 = (b) + 2048;  \
  const u16* _b2 = (b) + 4096;    const u16* _b3 = (b) + 6144;  \
  const u16* _b4 = (b) + 8192;    const u16* _b5 = (b) + 10240; \
  const u16* _b6 = (b) + 12288;   const u16* _b7 = (b) + 14336; \
  LD16T(arr[0],  _b0, 0); LD16T(arr[1],  _b0, 1024); \
  LD16T(arr[2],  _b0, 2048); LD16T(arr[3],  _b0, 3072); \
  LD16T(arr[4],  _b1, 0); LD16T(arr[5],  _b1, 1024); \
  LD16T(arr[6],  _b1, 2048); LD16T(arr[7],  _b1, 3072); \
  LD16T(arr[8],  _b2, 0); LD16T(arr[9],  _b2, 1024); \
  LD16T(arr[10], _b2, 2048); LD16T(arr[11], _b2, 3072); \
  LD16T(arr[12], _b3, 0); LD16T(arr[13], _b3, 1024); \
  LD16T(arr[14], _b3, 2048); LD16T(arr[15], _b3, 3072); \
  LD16T(arr[16], _b4, 0); LD16T(arr[17], _b4, 1024); \
  LD16T(arr[18], _b4, 2048); LD16T(arr[19], _b4, 3072); \
  LD16T(arr[20], _b5, 0); LD16T(arr[21], _b5, 1024); \
  LD16T(arr[22], _b5, 2048); LD16T(arr[23], _b5, 3072); \
  LD16T(arr[24], _b6, 0); LD16T(arr[25], _b6, 1024); \
  LD16T(arr[26], _b6, 2048); LD16T(arr[27], _b6, 3072); \
  LD16T(arr[28], _b7, 0); LD16T(arr[29], _b7, 1024); \
  LD16T(arr[30], _b7, 2048); LD16T(arr[31], _b7, 3072); \
} while (0)

// STORES: RETURNING atomic exchange — vmcnt ack == performed at the LLC.
__device__ __forceinline__ void st_u64_coh(u64* p, u64 v) {
  u64 r = __hip_atomic_exchange(p, v, __ATOMIC_RELAXED,
                                __HIP_MEMORY_SCOPE_AGENT);
  asm volatile("" :: "v"(r));  // keep returning form (no DCE to plain store)
}

__global__ __launch_bounds__(256) void init_kernel(float* hF, u16* hB, int* bar) {
  int i = blockIdx.x * 256 + threadIdx.x;
  hF[i] = 0.f;
  hB[i] = 0;
  if (i < 16384) bar[i] = 0;  // 16 domains x 1024 ints of flag state
}

// W [K_DIM][N] fp32 -> Wt [N][K_DIM] bf16
__global__ __launch_bounds__(256) void wconv_kernel(const float* __restrict__ W,
                                                    u16* __restrict__ Wt, int N) {
  int k = blockIdx.x * 64 + (threadIdx.x & 63);
  int n = blockIdx.y * 4 + (threadIdx.x >> 6);
  Wt[(size_t)n * K_DIM + k] = f2bf(W[(size_t)k * N + n]);
}

__global__ __launch_bounds__(128) void embed_kernel(const int* __restrict__ inp,
                                                    const float* __restrict__ emb,
                                                    u16* __restrict__ X) {
  int rb = blockIdx.x;
  int idx = inp[rb];
  int e = threadIdx.x * 4;
  float4 v = *(const float4*)&emb[(size_t)idx * E_DIM + e];
  ushort4 o;
  o.x = f2bf(v.x); o.y = f2bf(v.y); o.z = f2bf(v.z); o.w = f2bf(v.w);
  *(ushort4*)&X[(size_t)rb * E_DIM + e] = o;
}

// Swizzled LDS weight read: logical [48 cols][1536 k] bf16, row stride 3072 B.
__device__ __forceinline__ bf16x8 ldsW(const u16* Wl, int lc, int k) {
  int ofs = lc * 3072 + k * 2;
  ofs ^= ((lc & 7) << 4);
  return *(const bf16x8*)((const char*)Wl + ofs);
}

// WAVE-LOCAL rendezvous (new): domain = 16 rows, owned by ONE wave per ct.
// fdom[ct*8] = arrival flag of WG ct's wave for this domain (32-B spacing).
// Arrival: wave drains its own exchange-acks (vmcnt(0)), lane 0 posts flag.
// Wait: 64 lanes poll the 64 flags; divergent-exit loop reconverges only
// when ALL flags observed (wave lockstep), so any subsequent load issues
// after the full rendezvous. Per-lane data-dependent token (v>>30 == 0)
// gates load addresses — unhoistable by dataflow (r13-proven, per-lane).
// NO __syncthreads: the WG's 8 waves free-run on 8 independent domains;
// with 2 waves/SIMD a sleeping wave yields its SIMD to its co-tenant.
__device__ __forceinline__ void wave_arrive(int* fdom, int ct, int phase,
                                            int lane) {
  WAIT_VM_ALL();
  if (lane == 0) {
    int r = __hip_atomic_exchange(&fdom[ct * 8], phase, __ATOMIC_RELAXED,
                                  __HIP_MEMORY_SCOPE_AGENT);
    asm volatile("" :: "v"(r));
  }
}
__device__ __forceinline__ int wave_wait(int* fdom, int phase, int lane) {
  int v;
  do {
    v = __hip_atomic_load(&fdom[(lane & 63) * 8], __ATOMIC_RELAXED,
                          __HIP_MEMORY_SCOPE_AGENT);
    if (v >= phase) break;
    __builtin_amdgcn_s_sleep(1);
  } while (true);
  return v >> 30;  // 0; per-lane dataflow token
}

// Persistent GRU loop. Grid: 128 WGs x 512 thr (8 waves).
// WG = (ct in [0,64)) x (half in [0,2)). Wave wv owns domain d = half*8+wv
// (16 domains x 16 rows); rows [d*16, d*16+16).
// ct owns gate cols [ct*16,+16) (r) + [1024+ct*16,+16) (z) + cand [ct*16,+16);
// z and fp32 h master live in registers. Schedule per wave (r15):
//   post-b2: a0 h-part (32 MFMA) -> r -> rh exchange -> arrive(b1)
//   b1 window: z full GEMM (48 MFMA) + cand x-part (16 MFMA)
//   post-b1: cand h-part (32 MFMA) -> h update -> h exchange -> arrive(b2)
//   b2 window: af(t+1) load + gates-r x-part (16 MFMA, carried a0)
__global__ void __launch_bounds__(512, 2) gru_loop(
    const u16* __restrict__ X, const u16* __restrict__ WgT,
    const u16* __restrict__ WcT, const float* __restrict__ bg,
    const float* __restrict__ bc, float* __restrict__ hF,
    u16* __restrict__ hB, u16* __restrict__ rhB,
    const int* __restrict__ lens, int* bar) {
  __shared__ __align__(16) u16 Wl[48 * K_DIM];  // 147456 B
  const int tid = threadIdx.x;
  const int wgid = blockIdx.x;
  const int ct = wgid >> 1;
  const int half = wgid & 1;

  // Stage weights once: 48 cols x 1536 k (512 threads, 18 iters).
#pragma unroll 4
  for (int it = 0; it < 18; ++it) {
    int ci = it * 512 + tid;
    int lc = ci / 192;
    int k0 = (ci - lc * 192) * 8;
    const u16* src = (lc < 16)
        ? WgT + (size_t)(ct * 16 + lc) * K_DIM + k0
        : (lc < 32)
          ? WgT + (size_t)(1024 + ct * 16 + (lc - 16)) * K_DIM + k0
          : WcT + (size_t)(ct * 16 + (lc - 32)) * K_DIM + k0;
    uint4 v = *(const uint4*)src;
    int ofs = lc * 3072 + k0 * 2;
    ofs ^= ((lc & 7) << 4);
    *(uint4*)((char*)Wl + ofs) = v;
  }
  __syncthreads();  // one-time: weights visible to all 8 waves

  const int lane = tid & 63, wv = tid >> 6;
  const int l15 = lane & 15;
  const int kq8 = (lane >> 4) * 8;
  const int lq4 = (lane >> 4) * 4;
  const int d = half * 8 + wv;         // this wave's 16-row domain
  const int rbase = d * 16;
  const int tbase = (rbase >> 4) * 16384 + (lane >> 4) * 128 + l15 * 8;
  const u16* Hp = hB + tbase;
  const u16* Rp = rhB + tbase;
  int* fdom = bar + d * 1024;

  int len4[4];
#pragma unroll
  for (int q = 0; q < 4; ++q) len4[q] = lens[rbase + lq4 + q];
  const int nc = ct * 16 + l15;
  const float bg0 = bg[nc];
  const float bg1 = bg[1024 + nc];
  const float bc0 = bc[nc];
  u16* rhW = rhB + (rbase >> 4) * 16384 + (nc >> 3) * 128 + (nc & 7);
  u16* hW  = hB  + (rbase >> 4) * 16384 + (nc >> 3) * 128 + (nc & 7);

  float h_reg[4] = {0.f, 0.f, 0.f, 0.f};
  float z_reg[4];

  bf16x8 af[16], ah[32];
  // Prologue: af(0) + gates-r x-part (carried a0).
  f32x4 a0 = {0.f, 0.f, 0.f, 0.f};
  {
    const u16* Xt = X + ((size_t)0 * B_DIM + rbase + l15) * E_DIM + kq8;
#pragma unroll
    for (int kb = 0; kb < 16; ++kb) af[kb] = *(const bf16x8*)(Xt + kb * 32);
    WAIT_VM_ALL();
#pragma unroll
    for (int kb = 0; kb < 16; ++kb) {
      a0 = __builtin_amdgcn_mfma_f32_16x16x32_bf16(af[kb],
              ldsW(Wl, l15, kb * 32 + kq8), a0, 0, 0, 0);
    }
  }

  int phase = 0;
  int tok = 0;  // t=0 h from init_kernel (kernel-boundary coherence)
  for (int t = 0; t < T_DIM; ++t) {
    // ---- Phase A (post-b2): r-gate h-part only; rh exchange ----
    const u16* HpT = Hp + tok;
    LOAD32T(ah, HpT);
    WAIT_VM_ALL();
#pragma unroll
    for (int kb = 0; kb < 32; ++kb) {
      a0 = __builtin_amdgcn_mfma_f32_16x16x32_bf16(ah[kb],
              ldsW(Wl, l15, (kb + 16) * 32 + kq8), a0, 0, 0, 0);
    }
#pragma unroll
    for (int q = 0; q < 4; ++q) {
      float r = 1.f / (1.f + __expf(-(a0[q] + bg0)));
      u16 rv = f2bf(r * h_reg[q]);
      u32 lo = (u32)rv | ((u32)(u16)__shfl_xor((int)rv, 1) << 16);
      u32 hi = (u32)__shfl_xor((int)lo, 2);
      if ((l15 & 3) == 0) {
        st_u64_coh((u64*)(rhW + (lq4 + q) * 8), (u64)lo | ((u64)hi << 32));
      }
    }
    wave_arrive(fdom, ct, ++phase, lane);
    // ---- b1 window: z-gate full GEMM + cand x-part (ah still holds h) ----
    f32x4 a1 = {0.f, 0.f, 0.f, 0.f};
#pragma unroll
    for (int kb = 0; kb < 16; ++kb) {
      a1 = __builtin_amdgcn_mfma_f32_16x16x32_bf16(af[kb],
              ldsW(Wl, 16 + l15, kb * 32 + kq8), a1, 0, 0, 0);
    }
#pragma unroll
    for (int kb = 0; kb < 32; ++kb) {
      a1 = __builtin_amdgcn_mfma_f32_16x16x32_bf16(ah[kb],
              ldsW(Wl, 16 + l15, (kb + 16) * 32 + kq8), a1, 0, 0, 0);
    }
#pragma unroll
    for (int q = 0; q < 4; ++q)
      z_reg[q] = 1.f / (1.f + __expf(-(a1[q] + bg1)));
    f32x4 a2 = {0.f, 0.f, 0.f, 0.f};
#pragma unroll
    for (int kb = 0; kb < 16; ++kb) {
      a2 = __builtin_amdgcn_mfma_f32_16x16x32_bf16(af[kb],
              ldsW(Wl, 32 + l15, kb * 32 + kq8), a2, 0, 0, 0);
    }
    tok = wave_wait(fdom, phase, lane);

    // ---- Phase B (post-b1): cand h-part; h update; h exchange ----
    const u16* RpT = Rp + tok;
    LOAD32T(ah, RpT);
    WAIT_VM_ALL();
#pragma unroll
    for (int kb = 0; kb < 32; ++kb) {
      a2 = __builtin_amdgcn_mfma_f32_16x16x32_bf16(ah[kb],
              ldsW(Wl, 32 + l15, (kb + 16) * 32 + kq8), a2, 0, 0, 0);
    }
#pragma unroll
    for (int q = 0; q < 4; ++q) {
      int row = rbase + lq4 + q;
      float c = tanhf(a2[q] + bc0);
      float hn = z_reg[q] * h_reg[q] + (1.f - z_reg[q]) * c;
      float v = (t < len4[q]) ? hn : h_reg[q];
      h_reg[q] = v;
      u16 hv = f2bf(v);
      u32 lo = (u32)hv | ((u32)(u16)__shfl_xor((int)hv, 1) << 16);
      u32 hi = (u32)__shfl_xor((int)lo, 2);
      if ((l15 & 3) == 0) {
        st_u64_coh((u64*)(hW + (lq4 + q) * 8), (u64)lo | ((u64)hi << 32));
      }
      if (t == T_DIM - 1) {
        hF[(size_t)row * U_DIM + nc] = v;  // fp32 h for MLP (kernel boundary)
      }
    }
    wave_arrive(fdom, ct, ++phase, lane);
    // ---- b2 window: af(t+1) + gates-r x-part into carried a0 ----
    a0 = f32x4{0.f, 0.f, 0.f, 0.f};
    if (t + 1 < T_DIM) {
      const u16* Xt = X + ((size_t)(t + 1) * B_DIM + rbase + l15) * E_DIM + kq8;
#pragma unroll
      for (int kb = 0; kb < 16; ++kb) af[kb] = *(const bf16x8*)(Xt + kb * 32);
      WAIT_VM_ALL();
#pragma unroll
      for (int kb = 0; kb < 16; ++kb) {
        a0 = __builtin_amdgcn_mfma_f32_16x16x32_bf16(af[kb],
                ldsW(Wl, l15, kb * 32 + kq8), a0, 0, 0, 0);
      }
    }
    tok = wave_wait(fdom, phase, lane);
  }
}

__global__ __launch_bounds__(256) void mlp1_kernel(const float* __restrict__ h,
                                                   const float* __restrict__ W1,
                                                   const float* __restrict__ b1,
                                                   float* __restrict__ o1) {
  int m = blockIdx.x, tid = threadIdx.x;
  __shared__ float xs[1024];
  for (int k = tid; k < 1024; k += 256) xs[k] = h[(size_t)m * 1024 + k];
  __syncthreads();
  for (int n = tid; n < 512; n += 256) {
    float s = b1[n];
    for (int k = 0; k < 1024; ++k) s += xs[k] * W1[(size_t)k * 512 + n];
    o1[(size_t)m * 512 + n] = fmaxf(s, 0.f);
  }
}

__global__ __launch_bounds__(256) void mlp2_kernel(const float* __restrict__ x,
                                                   const float* __restrict__ W2,
                                                   const float* __restrict__ b2,
                                                   float* __restrict__ o2) {
  int m = blockIdx.x, tid = threadIdx.x;
  __shared__ float xs[512];
  for (int k = tid; k < 512; k += 256) xs[k] = x[(size_t)m * 512 + k];
  __syncthreads();
  int n = tid;
  float s = b2[n];
  for (int k = 0; k < 512; ++k) s += xs[k] * W2[(size_t)k * 256 + n];
  o2[(size_t)m * 256 + n] = fmaxf(s, 0.f);
}

__global__ __launch_bounds__(256) void mlp3_kernel(const float* __restrict__ x,
                                                   const float* __restrict__ W3,
                                                   const float* __restrict__ b3,
                                                   float* __restrict__ out) {
  int m = blockIdx.x, tid = threadIdx.x;
  float xk = x[(size_t)m * 256 + tid];
  float p0 = xk * W3[tid * 2 + 0];
  float p1 = xk * W3[tid * 2 + 1];
#pragma unroll
  for (int off = 32; off; off >>= 1) {
    p0 += __shfl_down(p0, off);
    p1 += __shfl_down(p1, off);
  }
  __shared__ float s0[4], s1[4];
  int wave = tid >> 6, lane = tid & 63;
  if (lane == 0) { s0[wave] = p0; s1[wave] = p1; }
  __syncthreads();
  if (tid == 0) {
    float l0 = s0[0] + s0[1] + s0[2] + s0[3] + b3[0];
    float l1 = s1[0] + s1[1] + s1[2] + s1[3] + b3[1];
    out[m * 2 + 0] = l0;
    out[m * 2 + 1] = l1;
    float mx = fmaxf(l0, l1);
    float e0 = __expf(l0 - mx), e1 = __expf(l1 - mx);
    float inv = 1.f / (e0 + e1);
    out[512 + m * 2 + 0] = e0 * inv;
    out[512 + m * 2 + 1] = e1 * inv;
  }
}

extern "C" void kernel_launch(void* const* d_in, const int* in_sizes, int n_in,
                              void* d_out, int out_size, void* d_ws, size_t ws_size,
                              hipStream_t stream) {
  (void)in_sizes; (void)n_in; (void)out_size; (void)ws_size;
  const int* inputs = (const int*)d_in[0];
  const int* lens = (const int*)d_in[1];
  const float* embedder = (const float*)d_in[2];
  const float* Wg = (const float*)d_in[3];
  const float* bg = (const float*)d_in[4];
  const float* Wc = (const float*)d_in[5];
  const float* bc = (const float*)d_in[6];
  const float* W1 = (const float*)d_in[7];
  const float* b1 = (const float*)d_in[8];
  const float* W2 = (const float*)d_in[9];
  const float* b2 = (const float*)d_in[10];
  const float* W3 = (const float*)d_in[11];
  const float* b3 = (const float*)d_in[12];
  float* out = (float*)d_out;

  char* ws = (char*)d_ws;
  size_t off = 0;
  u16* X = (u16*)(ws + off);       off += (size_t)T_DIM * B_DIM * E_DIM * 2;
  u16* WgT = (u16*)(ws + off);     off += (size_t)NG * K_DIM * 2;
  u16* WcT = (u16*)(ws + off);     off += (size_t)U_DIM * K_DIM * 2;
  float* hF = (float*)(ws + off);  off += (size_t)B_DIM * U_DIM * 4;
  u16* hB = (u16*)(ws + off);      off += (size_t)B_DIM * U_DIM * 2;
  u16* rhB = (u16*)(ws + off);     off += (size_t)B_DIM * U_DIM * 2;
  float* o1 = (float*)(ws + off);  off += (size_t)B_DIM * 512 * 4;
  float* o2 = (float*)(ws + off);  off += (size_t)B_DIM * 256 * 4;
  int* bar = (int*)(ws + off);     off += 65536;

  init_kernel<<<dim3(1024), dim3(256), 0, stream>>>(hF, hB, bar);
  wconv_kernel<<<dim3(24, 512), dim3(256), 0, stream>>>(Wg, WgT, NG);
  wconv_kernel<<<dim3(24, 256), dim3(256), 0, stream>>>(Wc, WcT, U_DIM);
  embed_kernel<<<dim3(T_DIM * B_DIM), dim3(128), 0, stream>>>(inputs, embedder, X);

  gru_loop<<<dim3(NWG), dim3(512), 0, stream>>>(X, WgT, WcT, bg, bc, hF, hB, rhB,
                                                lens, bar);

  mlp1_kernel<<<dim3(256), dim3(256), 0, stream>>>(hF, W1, b1, o1);
  mlp2_kernel<<<dim3(256), dim3(256), 0, stream>>>(o1, W2, b2, o2);
  mlp3_kernel<<<dim3(256), dim3(256), 0, stream>>>(o2, W3, b3, out);
}

// Round 17
// 7035.561 us; speedup vs baseline: 3.2927x; 3.2927x over previous
//
#include <hip/hip_runtime.h>

typedef unsigned short u16;
typedef unsigned int u32;
typedef unsigned long long u64;

using bf16x8 = __attribute__((ext_vector_type(8))) __bf16;
using f32x4  = __attribute__((ext_vector_type(4))) float;

#define T_DIM 512
#define B_DIM 256
#define E_DIM 512
#define U_DIM 1024
#define K_DIM 1536   /* E+U */
#define NG    2048   /* 2U */
#define NWG   256    /* persistent grid: 1 WG/CU on all 256 CUs */

__device__ __forceinline__ u16 f2bf(float f) {
  union { float f; u32 u; } v; v.f = f;
  return (u16)((v.u + 0x7fffu + ((v.u >> 16) & 1u)) >> 16);
}

// ---- device-coherent cross-WG traffic (r14-proven).
// h/rh transposed layout hT[row/16][k/8][row%16][8] (u16):
//   elem_addr = (row>>4)*16384 + (k>>3)*128 + (row&15)*8 + (k&7)
// One wave load instruction covers 1024 contiguous B = 8 lines.
#define WAIT_VM_ALL() do { asm volatile("s_waitcnt vmcnt(0)" ::: "memory"); \
                           __builtin_amdgcn_sched_barrier(0); } while (0)

#define LD16T(dst, base, OFS) \
  asm volatile("global_load_dwordx4 %0, %1, off offset:" #OFS " sc0 sc1" \
               : "=&v"(dst) : "v"(base))

#define LOAD32T(arr, b) do { \
  const u16* _b0 = (b);           const u16* _b1 = (b) + 2048;  \
  const u16* _b2 = (b) + 4096;    const u16* _b3 = (b) + 6144;  \
  const u16* _b4 = (b) + 8192;    const u16* _b5 = (b) + 10240; \
  const u16* _b6 = (b) + 12288;   const u16* _b7 = (b) + 14336; \
  LD16T(arr[0],  _b0, 0); LD16T(arr[1],  _b0, 1024); \
  LD16T(arr[2],  _b0, 2048); LD16T(arr[3],  _b0, 3072); \
  LD16T(arr[4],  _b1, 0); LD16T(arr[5],  _b1, 1024); \
  LD16T(arr[6],  _b1, 2048); LD16T(arr[7],  _b1, 3072); \
  LD16T(arr[8],  _b2, 0); LD16T(arr[9],  _b2, 1024); \
  LD16T(arr[10], _b2, 2048); LD16T(arr[11], _b2, 3072); \
  LD16T(arr[12], _b3, 0); LD16T(arr[13], _b3, 1024); \
  LD16T(arr[14], _b3, 2048); LD16T(arr[15], _b3, 3072); \
  LD16T(arr[16], _b4, 0); LD16T(arr[17], _b4, 1024); \
  LD16T(arr[18], _b4, 2048); LD16T(arr[19], _b4, 3072); \
  LD16T(arr[20], _b5, 0); LD16T(arr[21], _b5, 1024); \
  LD16T(arr[22], _b5, 2048); LD16T(arr[23], _b5, 3072); \
  LD16T(arr[24], _b6, 0); LD16T(arr[25], _b6, 1024); \
  LD16T(arr[26], _b6, 2048); LD16T(arr[27], _b6, 3072); \
  LD16T(arr[28], _b7, 0); LD16T(arr[29], _b7, 1024); \
  LD16T(arr[30], _b7, 2048); LD16T(arr[31], _b7, 3072); \
} while (0)

// STORES: RETURNING atomic exchange — vmcnt ack == performed at the LLC.
__device__ __forceinline__ void st_u64_coh(u64* p, u64 v) {
  u64 r = __hip_atomic_exchange(p, v, __ATOMIC_RELAXED,
                                __HIP_MEMORY_SCOPE_AGENT);
  asm volatile("" :: "v"(r));  // keep returning form (no DCE to plain store)
}

__global__ __launch_bounds__(256) void init_kernel(float* hF, u16* hB, int* bar) {
  int i = blockIdx.x * 256 + threadIdx.x;
  hF[i] = 0.f;
  hB[i] = 0;
  if (i < 8192) bar[i] = 0;  // 4 domains x 2048 ints (256 flags x 8 ints)
}

// W [K_DIM][N] fp32 -> Wt [N][K_DIM] bf16
__global__ __launch_bounds__(256) void wconv_kernel(const float* __restrict__ W,
                                                    u16* __restrict__ Wt, int N) {
  int k = blockIdx.x * 64 + (threadIdx.x & 63);
  int n = blockIdx.y * 4 + (threadIdx.x >> 6);
  Wt[(size_t)n * K_DIM + k] = f2bf(W[(size_t)k * N + n]);
}

__global__ __launch_bounds__(128) void embed_kernel(const int* __restrict__ inp,
                                                    const float* __restrict__ emb,
                                                    u16* __restrict__ X) {
  int rb = blockIdx.x;
  int idx = inp[rb];
  int e = threadIdx.x * 4;
  float4 v = *(const float4*)&emb[(size_t)idx * E_DIM + e];
  ushort4 o;
  o.x = f2bf(v.x); o.y = f2bf(v.y); o.z = f2bf(v.z); o.w = f2bf(v.w);
  *(ushort4*)&X[(size_t)rb * E_DIM + e] = o;
}

// Swizzled LDS weight read: logical [48 cols][1536 k] bf16, row stride 3072 B.
__device__ __forceinline__ bf16x8 ldsW(const u16* Wl, int lc, int k) {
  int ofs = lc * 3072 + k * 2;
  ofs ^= ((lc & 7) << 4);
  return *(const bf16x8*)((const char*)Wl + ofs);
}

// PER-WAVE arrival: each wave drains its own exchange-acks (vmcnt(0))
// then lane 0 posts its flag — 4 flags/WG, 256/domain at 32-B spacing.
// Ordering: wave's data exchanges acked at LLC before its flag issues;
// consumers require ALL 256 flags.
__device__ __forceinline__ void wave_arrive(int* fbase, int ct, int wv,
                                            int phase, int lane) {
  WAIT_VM_ALL();
  if (lane == 0) {
    int r = __hip_atomic_exchange(&fbase[(ct * 4 + wv) * 8], phase,
                                  __ATOMIC_RELAXED, __HIP_MEMORY_SCOPE_AGENT);
    asm volatile("" :: "v"(r));
  }
}
// Poll: all 256 threads spin on one flag each; thread 0 publishes the
// data-dependent token (always 0) through LDS — adding it to a load base
// makes that load's address depend on barrier completion (unhoistable).
__device__ __forceinline__ int barrier_wait(int* fbase, int phase,
                                            int* sh_tok) {
  int v;
  do {
    v = __hip_atomic_load(&fbase[threadIdx.x * 8], __ATOMIC_RELAXED,
                          __HIP_MEMORY_SCOPE_AGENT);
    if (v >= phase) break;
    __builtin_amdgcn_s_sleep(1);
  } while (true);
  if (threadIdx.x == 0) *sh_tok = (v >> 30);  // 0, dataflow from the spin
  __syncthreads();
  return *sh_tok;
}

// Persistent GRU loop. Grid: 256 WGs x 256 thr.
// WG = (col-tile ct in [0,64)) x (row-quarter mq in [0,4)); rows [mq*64,+64).
// ct owns gate cols [ct*16,+16) (r) + [1024+ct*16,+16) (z) + cand [ct*16,+16);
// z and fp32 h master live in registers. Schedule:
//   post-b2: a0 h-part (32 MFMA) -> r -> rh exchange -> wave arrive(b1)
//   b1 window: z full GEMM (48 MFMA) + cand x-part (16 MFMA)
//   post-b1: cand h-part (32 MFMA) -> h update -> h exchange -> arrive(b2)
//   b2 window: af(t+1) load + gates-r x-part (16 MFMA, carried a0)
__global__ void __launch_bounds__(256, 1) gru_loop(
    const u16* __restrict__ X, const u16* __restrict__ WgT,
    const u16* __restrict__ WcT, const float* __restrict__ bg,
    const float* __restrict__ bc, float* __restrict__ hF,
    u16* __restrict__ hB, u16* __restrict__ rhB,
    const int* __restrict__ lens, int* bar) {
  __shared__ __align__(16) u16 Wl[48 * K_DIM];  // 147456 B
  __shared__ int sh_tok;
  const int tid = threadIdx.x;
  const int wgid = blockIdx.x;
  const int ct = wgid >> 2;
  const int mq = wgid & 3;

  // Stage weights once: 48 cols x 1536 k.
#pragma unroll 4
  for (int it = 0; it < 36; ++it) {
    int ci = it * 256 + tid;
    int lc = ci / 192;
    int k0 = (ci - lc * 192) * 8;
    const u16* src = (lc < 16)
        ? WgT + (size_t)(ct * 16 + lc) * K_DIM + k0
        : (lc < 32)
          ? WgT + (size_t)(1024 + ct * 16 + (lc - 16)) * K_DIM + k0
          : WcT + (size_t)(ct * 16 + (lc - 32)) * K_DIM + k0;
    uint4 v = *(const uint4*)src;
    int ofs = lc * 3072 + k0 * 2;
    ofs ^= ((lc & 7) << 4);
    *(uint4*)((char*)Wl + ofs) = v;
  }
  __syncthreads();

  const int lane = tid & 63, wv = tid >> 6;
  const int l15 = lane & 15;
  const int kq8 = (lane >> 4) * 8;
  const int lq4 = (lane >> 4) * 4;
  const int rbase = mq * 64 + wv * 16;
  const int tbase = (rbase >> 4) * 16384 + (lane >> 4) * 128 + l15 * 8;
  const u16* Hp = hB + tbase;
  const u16* Rp = rhB + tbase;
  int* fbase = bar + mq * 2048;

  int len4[4];
#pragma unroll
  for (int q = 0; q < 4; ++q) len4[q] = lens[rbase + lq4 + q];
  const int nc = ct * 16 + l15;
  const float bg0 = bg[nc];
  const float bg1 = bg[1024 + nc];
  const float bc0 = bc[nc];
  u16* rhW = rhB + (rbase >> 4) * 16384 + (nc >> 3) * 128 + (nc & 7);
  u16* hW  = hB  + (rbase >> 4) * 16384 + (nc >> 3) * 128 + (nc & 7);

  float h_reg[4] = {0.f, 0.f, 0.f, 0.f};
  float z_reg[4];

  bf16x8 af[16], ah[32];
  // Prologue: af(0) + gates-r x-part (carried a0).
  f32x4 a0 = {0.f, 0.f, 0.f, 0.f};
  {
    const u16* Xt = X + ((size_t)0 * B_DIM + rbase + l15) * E_DIM + kq8;
#pragma unroll
    for (int kb = 0; kb < 16; ++kb) af[kb] = *(const bf16x8*)(Xt + kb * 32);
    WAIT_VM_ALL();
#pragma unroll
    for (int kb = 0; kb < 16; ++kb) {
      a0 = __builtin_amdgcn_mfma_f32_16x16x32_bf16(af[kb],
              ldsW(Wl, l15, kb * 32 + kq8), a0, 0, 0, 0);
    }
  }

  int phase = 0;
  int tok = 0;  // t=0 h from init_kernel (kernel-boundary coherence)
  for (int t = 0; t < T_DIM; ++t) {
    // ---- Phase A (post-b2): r-gate h-part only; rh exchange ----
    const u16* HpT = Hp + tok;
    LOAD32T(ah, HpT);
    WAIT_VM_ALL();
#pragma unroll
    for (int kb = 0; kb < 32; ++kb) {
      a0 = __builtin_amdgcn_mfma_f32_16x16x32_bf16(ah[kb],
              ldsW(Wl, l15, (kb + 16) * 32 + kq8), a0, 0, 0, 0);
    }
#pragma unroll
    for (int q = 0; q < 4; ++q) {
      float r = 1.f / (1.f + __expf(-(a0[q] + bg0)));
      u16 rv = f2bf(r * h_reg[q]);
      u32 lo = (u32)rv | ((u32)(u16)__shfl_xor((int)rv, 1) << 16);
      u32 hi = (u32)__shfl_xor((int)lo, 2);
      if ((l15 & 3) == 0) {
        st_u64_coh((u64*)(rhW + (lq4 + q) * 8), (u64)lo | ((u64)hi << 32));
      }
    }
    wave_arrive(fbase, ct, wv, ++phase, lane);
    // ---- b1 window: z-gate full GEMM + cand x-part (ah still holds h) ----
    f32x4 a1 = {0.f, 0.f, 0.f, 0.f};
#pragma unroll
    for (int kb = 0; kb < 16; ++kb) {
      a1 = __builtin_amdgcn_mfma_f32_16x16x32_bf16(af[kb],
              ldsW(Wl, 16 + l15, kb * 32 + kq8), a1, 0, 0, 0);
    }
#pragma unroll
    for (int kb = 0; kb < 32; ++kb) {
      a1 = __builtin_amdgcn_mfma_f32_16x16x32_bf16(ah[kb],
              ldsW(Wl, 16 + l15, (kb + 16) * 32 + kq8), a1, 0, 0, 0);
    }
#pragma unroll
    for (int q = 0; q < 4; ++q)
      z_reg[q] = 1.f / (1.f + __expf(-(a1[q] + bg1)));
    f32x4 a2 = {0.f, 0.f, 0.f, 0.f};
#pragma unroll
    for (int kb = 0; kb < 16; ++kb) {
      a2 = __builtin_amdgcn_mfma_f32_16x16x32_bf16(af[kb],
              ldsW(Wl, 32 + l15, kb * 32 + kq8), a2, 0, 0, 0);
    }
    tok = barrier_wait(fbase, phase, &sh_tok);

    // ---- Phase B (post-b1): cand h-part; h update; h exchange ----
    const u16* RpT = Rp + tok;
    LOAD32T(ah, RpT);
    WAIT_VM_ALL();
#pragma unroll
    for (int kb = 0; kb < 32; ++kb) {
      a2 = __builtin_amdgcn_mfma_f32_16x16x32_bf16(ah[kb],
              ldsW(Wl, 32 + l15, (kb + 16) * 32 + kq8), a2, 0, 0, 0);
    }
#pragma unroll
    for (int q = 0; q < 4; ++q) {
      int row = rbase + lq4 + q;
      float c = tanhf(a2[q] + bc0);
      float hn = z_reg[q] * h_reg[q] + (1.f - z_reg[q]) * c;
      float v = (t < len4[q]) ? hn : h_reg[q];
      h_reg[q] = v;
      u16 hv = f2bf(v);
      u32 lo = (u32)hv | ((u32)(u16)__shfl_xor((int)hv, 1) << 16);
      u32 hi = (u32)__shfl_xor((int)lo, 2);
      if ((l15 & 3) == 0) {
        st_u64_coh((u64*)(hW + (lq4 + q) * 8), (u64)lo | ((u64)hi << 32));
      }
      if (t == T_DIM - 1) {
        hF[(size_t)row * U_DIM + nc] = v;  // fp32 h for MLP (kernel boundary)
      }
    }
    wave_arrive(fbase, ct, wv, ++phase, lane);
    // ---- b2 window: af(t+1) + gates-r x-part into carried a0 ----
    a0 = f32x4{0.f, 0.f, 0.f, 0.f};
    if (t + 1 < T_DIM) {
      const u16* Xt = X + ((size_t)(t + 1) * B_DIM + rbase + l15) * E_DIM + kq8;
#pragma unroll
      for (int kb = 0; kb < 16; ++kb) af[kb] = *(const bf16x8*)(Xt + kb * 32);
      WAIT_VM_ALL();
#pragma unroll
      for (int kb = 0; kb < 16; ++kb) {
        a0 = __builtin_amdgcn_mfma_f32_16x16x32_bf16(af[kb],
                ldsW(Wl, l15, kb * 32 + kq8), a0, 0, 0, 0);
      }
    }
    tok = barrier_wait(fbase, phase, &sh_tok);
  }
}

__global__ __launch_bounds__(256) void mlp1_kernel(const float* __restrict__ h,
                                                   const float* __restrict__ W1,
                                                   const float* __restrict__ b1,
                                                   float* __restrict__ o1) {
  int m = blockIdx.x, tid = threadIdx.x;
  __shared__ float xs[1024];
  for (int k = tid; k < 1024; k += 256) xs[k] = h[(size_t)m * 1024 + k];
  __syncthreads();
  for (int n = tid; n < 512; n += 256) {
    float s = b1[n];
    for (int k = 0; k < 1024; ++k) s += xs[k] * W1[(size_t)k * 512 + n];
    o1[(size_t)m * 512 + n] = fmaxf(s, 0.f);
  }
}

__global__ __launch_bounds__(256) void mlp2_kernel(const float* __restrict__ x,
                                                   const float* __restrict__ W2,
                                                   const float* __restrict__ b2,
                                                   float* __restrict__ o2) {
  int m = blockIdx.x, tid = threadIdx.x;
  __shared__ float xs[512];
  for (int k = tid; k < 512; k += 256) xs[k] = x[(size_t)m * 512 + k];
  __syncthreads();
  int n = tid;
  float s = b2[n];
  for (int k = 0; k < 512; ++k) s += xs[k] * W2[(size_t)k * 256 + n];
  o2[(size_t)m * 256 + n] = fmaxf(s, 0.f);
}

__global__ __launch_bounds__(256) void mlp3_kernel(const float* __restrict__ x,
                                                   const float* __restrict__ W3,
                                                   const float* __restrict__ b3,
                                                   float* __restrict__ out) {
  int m = blockIdx.x, tid = threadIdx.x;
  float xk = x[(size_t)m * 256 + tid];
  float p0 = xk * W3[tid * 2 + 0];
  float p1 = xk * W3[tid * 2 + 1];
#pragma unroll
  for (int off = 32; off; off >>= 1) {
    p0 += __shfl_down(p0, off);
    p1 += __shfl_down(p1, off);
  }
  __shared__ float s0[4], s1[4];
  int wave = tid >> 6, lane = tid & 63;
  if (lane == 0) { s0[wave] = p0; s1[wave] = p1; }
  __syncthreads();
  if (tid == 0) {
    float l0 = s0[0] + s0[1] + s0[2] + s0[3] + b3[0];
    float l1 = s1[0] + s1[1] + s1[2] + s1[3] + b3[1];
    out[m * 2 + 0] = l0;
    out[m * 2 + 1] = l1;
    float mx = fmaxf(l0, l1);
    float e0 = __expf(l0 - mx), e1 = __expf(l1 - mx);
    float inv = 1.f / (e0 + e1);
    out[512 + m * 2 + 0] = e0 * inv;
    out[512 + m * 2 + 1] = e1 * inv;
  }
}

extern "C" void kernel_launch(void* const* d_in, const int* in_sizes, int n_in,
                              void* d_out, int out_size, void* d_ws, size_t ws_size,
                              hipStream_t stream) {
  (void)in_sizes; (void)n_in; (void)out_size; (void)ws_size;
  const int* inputs = (const int*)d_in[0];
  const int* lens = (const int*)d_in[1];
  const float* embedder = (const float*)d_in[2];
  const float* Wg = (const float*)d_in[3];
  const float* bg = (const float*)d_in[4];
  const float* Wc = (const float*)d_in[5];
  const float* bc = (const float*)d_in[6];
  const float* W1 = (const float*)d_in[7];
  const float* b1 = (const float*)d_in[8];
  const float* W2 = (const float*)d_in[9];
  const float* b2 = (const float*)d_in[10];
  const float* W3 = (const float*)d_in[11];
  const float* b3 = (const float*)d_in[12];
  float* out = (float*)d_out;

  char* ws = (char*)d_ws;
  size_t off = 0;
  u16* X = (u16*)(ws + off);       off += (size_t)T_DIM * B_DIM * E_DIM * 2;
  u16* WgT = (u16*)(ws + off);     off += (size_t)NG * K_DIM * 2;
  u16* WcT = (u16*)(ws + off);     off += (size_t)U_DIM * K_DIM * 2;
  float* hF = (float*)(ws + off);  off += (size_t)B_DIM * U_DIM * 4;
  u16* hB = (u16*)(ws + off);      off += (size_t)B_DIM * U_DIM * 2;
  u16* rhB = (u16*)(ws + off);     off += (size_t)B_DIM * U_DIM * 2;
  float* o1 = (float*)(ws + off);  off += (size_t)B_DIM * 512 * 4;
  float* o2 = (float*)(ws + off);  off += (size_t)B_DIM * 256 * 4;
  int* bar = (int*)(ws + off);     off += 65536;

  init_kernel<<<dim3(1024), dim3(256), 0, stream>>>(hF, hB, bar);
  wconv_kernel<<<dim3(24, 512), dim3(256), 0, stream>>>(Wg, WgT, NG);
  wconv_kernel<<<dim3(24, 256), dim3(256), 0, stream>>>(Wc, WcT, U_DIM);
  embed_kernel<<<dim3(T_DIM * B_DIM), dim3(128), 0, stream>>>(inputs, embedder, X);

  gru_loop<<<dim3(NWG), dim3(256), 0, stream>>>(X, WgT, WcT, bg, bc, hF, hB, rhB,
                                                lens, bar);

  mlp1_kernel<<<dim3(256), dim3(256), 0, stream>>>(hF, W1, b1, o1);
  mlp2_kernel<<<dim3(256), dim3(256), 0, stream>>>(o1, W2, b2, o2);
  mlp3_kernel<<<dim3(256), dim3(256), 0, stream>>>(o2, W3, b3, out);
}

// Round 18
// 6249.490 us; speedup vs baseline: 3.7069x; 1.1258x over previous
//
#include <hip/hip_runtime.h>

typedef unsigned short u16;
typedef unsigned int u32;
typedef unsigned long long u64;

using bf16x8 = __attribute__((ext_vector_type(8))) __bf16;
using f32x4  = __attribute__((ext_vector_type(4))) float;

#define T_DIM 512
#define B_DIM 256
#define E_DIM 512
#define U_DIM 1024
#define K_DIM 1536   /* E+U */
#define NG    2048   /* 2U */
#define NWG   256    /* persistent grid: 1 WG/CU on all 256 CUs */

__device__ __forceinline__ u16 f2bf(float f) {
  union { float f; u32 u; } v; v.f = f;
  return (u16)((v.u + 0x7fffu + ((v.u >> 16) & 1u)) >> 16);
}

// ---- device-coherent cross-WG traffic (r14-proven).
// h/rh transposed layout hT[row/16][k/8][row%16][8] (u16):
//   elem_addr = (row>>4)*16384 + (k>>3)*128 + (row&15)*8 + (k&7)
// One wave load instruction covers 1024 contiguous B = 8 lines.
#define WAIT_VM_ALL() do { asm volatile("s_waitcnt vmcnt(0)" ::: "memory"); \
                           __builtin_amdgcn_sched_barrier(0); } while (0)

#define LD16T(dst, base, OFS) \
  asm volatile("global_load_dwordx4 %0, %1, off offset:" #OFS " sc0 sc1" \
               : "=&v"(dst) : "v"(base))

#define LOAD32T(arr, b) do { \
  const u16* _b0 = (b);           const u16* _b1 = (b) + 2048;  \
  const u16* _b2 = (b) + 4096;    const u16* _b3 = (b) + 6144;  \
  const u16* _b4 = (b) + 8192;    const u16* _b5 = (b) + 10240; \
  const u16* _b6 = (b) + 12288;   const u16* _b7 = (b) + 14336; \
  LD16T(arr[0],  _b0, 0); LD16T(arr[1],  _b0, 1024); \
  LD16T(arr[2],  _b0, 2048); LD16T(arr[3],  _b0, 3072); \
  LD16T(arr[4],  _b1, 0); LD16T(arr[5],  _b1, 1024); \
  LD16T(arr[6],  _b1, 2048); LD16T(arr[7],  _b1, 3072); \
  LD16T(arr[8],  _b2, 0); LD16T(arr[9],  _b2, 1024); \
  LD16T(arr[10], _b2, 2048); LD16T(arr[11], _b2, 3072); \
  LD16T(arr[12], _b3, 0); LD16T(arr[13], _b3, 1024); \
  LD16T(arr[14], _b3, 2048); LD16T(arr[15], _b3, 3072); \
  LD16T(arr[16], _b4, 0); LD16T(arr[17], _b4, 1024); \
  LD16T(arr[18], _b4, 2048); LD16T(arr[19], _b4, 3072); \
  LD16T(arr[20], _b5, 0); LD16T(arr[21], _b5, 1024); \
  LD16T(arr[22], _b5, 2048); LD16T(arr[23], _b5, 3072); \
  LD16T(arr[24], _b6, 0); LD16T(arr[25], _b6, 1024); \
  LD16T(arr[26], _b6, 2048); LD16T(arr[27], _b6, 3072); \
  LD16T(arr[28], _b7, 0); LD16T(arr[29], _b7, 1024); \
  LD16T(arr[30], _b7, 2048); LD16T(arr[31], _b7, 3072); \
} while (0)

// STORES: RETURNING atomic exchange — vmcnt ack == performed at the LLC.
__device__ __forceinline__ void st_u64_coh(u64* p, u64 v) {
  u64 r = __hip_atomic_exchange(p, v, __ATOMIC_RELAXED,
                                __HIP_MEMORY_SCOPE_AGENT);
  asm volatile("" :: "v"(r));  // keep returning form (no DCE to plain store)
}

__global__ __launch_bounds__(256) void init_kernel(float* hF, u16* hB, int* bar) {
  int i = blockIdx.x * 256 + threadIdx.x;
  hF[i] = 0.f;
  hB[i] = 0;
  if (i < 16384) bar[i] = 0;  // 16 domains x 1024 ints (64 flags x 8 ints ea)
}

// W [K_DIM][N] fp32 -> Wt [N][K_DIM] bf16
__global__ __launch_bounds__(256) void wconv_kernel(const float* __restrict__ W,
                                                    u16* __restrict__ Wt, int N) {
  int k = blockIdx.x * 64 + (threadIdx.x & 63);
  int n = blockIdx.y * 4 + (threadIdx.x >> 6);
  Wt[(size_t)n * K_DIM + k] = f2bf(W[(size_t)k * N + n]);
}

__global__ __launch_bounds__(128) void embed_kernel(const int* __restrict__ inp,
                                                    const float* __restrict__ emb,
                                                    u16* __restrict__ X) {
  int rb = blockIdx.x;
  int idx = inp[rb];
  int e = threadIdx.x * 4;
  float4 v = *(const float4*)&emb[(size_t)idx * E_DIM + e];
  ushort4 o;
  o.x = f2bf(v.x); o.y = f2bf(v.y); o.z = f2bf(v.z); o.w = f2bf(v.w);
  *(ushort4*)&X[(size_t)rb * E_DIM + e] = o;
}

// Swizzled LDS weight read: logical [48 cols][1536 k] bf16, row stride 3072 B.
__device__ __forceinline__ bf16x8 ldsW(const u16* Wl, int lc, int k) {
  int ofs = lc * 3072 + k * 2;
  ofs ^= ((lc & 7) << 4);
  return *(const bf16x8*)((const char*)Wl + ofs);
}

// WAVE-LOCAL rendezvous (r16 concept, VGPR-safe shell): sync domain = 16
// rows, i.e. wave wv of row-quarter mq (d = mq*4+wv). The consumer of rows
// [d*16,+16) needs ONLY the same-16-row wave of each of the 64 cts — so each
// rendezvous is 64 flags, not 256, and the WG's 4 waves drift independently
// (no __syncthreads in the t-loop).
// Arrival: wave drains its exchange-acks (vmcnt(0)), lane 0 posts flag[d][ct].
// Wait: 64 lanes poll the domain's 64 flags; divergent-exit loop reconverges
// (wave lockstep) only when all observed; per-lane data-dependent token
// (v>>30 == 0) gates the next loads' addresses — unhoistable by dataflow.
__device__ __forceinline__ void wave_arrive(int* fdom, int ct, int phase,
                                            int lane) {
  WAIT_VM_ALL();
  if (lane == 0) {
    int r = __hip_atomic_exchange(&fdom[ct * 8], phase, __ATOMIC_RELAXED,
                                  __HIP_MEMORY_SCOPE_AGENT);
    asm volatile("" :: "v"(r));
  }
}
__device__ __forceinline__ int wave_wait(int* fdom, int phase, int lane) {
  int v;
  do {
    v = __hip_atomic_load(&fdom[(lane & 63) * 8], __ATOMIC_RELAXED,
                          __HIP_MEMORY_SCOPE_AGENT);
    if (v >= phase) break;
    __builtin_amdgcn_s_sleep(1);
  } while (true);
  return v >> 30;  // 0; per-lane dataflow token
}

// Persistent GRU loop. Grid: 256 WGs x 256 thr (r17 shell, VGPR ~204).
// WG = (col-tile ct in [0,64)) x (row-quarter mq in [0,4)); rows [mq*64,+64).
// ct owns gate cols [ct*16,+16) (r) + [1024+ct*16,+16) (z) + cand [ct*16,+16);
// z and fp32 h master live in registers. Schedule:
//   post-b2: a0 h-part (32 MFMA) -> r -> rh exchange -> wave arrive(b1)
//   b1 window: z full GEMM (48 MFMA) + cand x-part (16 MFMA)
//   post-b1: cand h-part (32 MFMA) -> h update -> h exchange -> arrive(b2)
//   b2 window: af(t+1) load + gates-r x-part (16 MFMA, carried a0)
__global__ void __launch_bounds__(256, 1) gru_loop(
    const u16* __restrict__ X, const u16* __restrict__ WgT,
    const u16* __restrict__ WcT, const float* __restrict__ bg,
    const float* __restrict__ bc, float* __restrict__ hF,
    u16* __restrict__ hB, u16* __restrict__ rhB,
    const int* __restrict__ lens, int* bar) {
  __shared__ __align__(16) u16 Wl[48 * K_DIM];  // 147456 B
  const int tid = threadIdx.x;
  const int wgid = blockIdx.x;
  const int ct = wgid >> 2;
  const int mq = wgid & 3;

  // Stage weights once: 48 cols x 1536 k.
#pragma unroll 4
  for (int it = 0; it < 36; ++it) {
    int ci = it * 256 + tid;
    int lc = ci / 192;
    int k0 = (ci - lc * 192) * 8;
    const u16* src = (lc < 16)
        ? WgT + (size_t)(ct * 16 + lc) * K_DIM + k0
        : (lc < 32)
          ? WgT + (size_t)(1024 + ct * 16 + (lc - 16)) * K_DIM + k0
          : WcT + (size_t)(ct * 16 + (lc - 32)) * K_DIM + k0;
    uint4 v = *(const uint4*)src;
    int ofs = lc * 3072 + k0 * 2;
    ofs ^= ((lc & 7) << 4);
    *(uint4*)((char*)Wl + ofs) = v;
  }
  __syncthreads();  // one-time: weights visible to all 4 waves

  const int lane = tid & 63, wv = tid >> 6;
  const int l15 = lane & 15;
  const int kq8 = (lane >> 4) * 8;
  const int lq4 = (lane >> 4) * 4;
  const int rbase = mq * 64 + wv * 16;
  const int tbase = (rbase >> 4) * 16384 + (lane >> 4) * 128 + l15 * 8;
  const u16* Hp = hB + tbase;
  const u16* Rp = rhB + tbase;
  int* fdom = bar + (mq * 4 + wv) * 1024;  // this wave's 16-row sync domain

  int len4[4];
#pragma unroll
  for (int q = 0; q < 4; ++q) len4[q] = lens[rbase + lq4 + q];
  const int nc = ct * 16 + l15;
  const float bg0 = bg[nc];
  const float bg1 = bg[1024 + nc];
  const float bc0 = bc[nc];
  u16* rhW = rhB + (rbase >> 4) * 16384 + (nc >> 3) * 128 + (nc & 7);
  u16* hW  = hB  + (rbase >> 4) * 16384 + (nc >> 3) * 128 + (nc & 7);

  float h_reg[4] = {0.f, 0.f, 0.f, 0.f};
  float z_reg[4];

  bf16x8 af[16], ah[32];
  // Prologue: af(0) + gates-r x-part (carried a0).
  f32x4 a0 = {0.f, 0.f, 0.f, 0.f};
  {
    const u16* Xt = X + ((size_t)0 * B_DIM + rbase + l15) * E_DIM + kq8;
#pragma unroll
    for (int kb = 0; kb < 16; ++kb) af[kb] = *(const bf16x8*)(Xt + kb * 32);
    WAIT_VM_ALL();
#pragma unroll
    for (int kb = 0; kb < 16; ++kb) {
      a0 = __builtin_amdgcn_mfma_f32_16x16x32_bf16(af[kb],
              ldsW(Wl, l15, kb * 32 + kq8), a0, 0, 0, 0);
    }
  }

  int phase = 0;
  int tok = 0;  // t=0 h from init_kernel (kernel-boundary coherence)
  for (int t = 0; t < T_DIM; ++t) {
    // ---- Phase A (post-b2): r-gate h-part only; rh exchange ----
    const u16* HpT = Hp + tok;
    LOAD32T(ah, HpT);
    WAIT_VM_ALL();
#pragma unroll
    for (int kb = 0; kb < 32; ++kb) {
      a0 = __builtin_amdgcn_mfma_f32_16x16x32_bf16(ah[kb],
              ldsW(Wl, l15, (kb + 16) * 32 + kq8), a0, 0, 0, 0);
    }
#pragma unroll
    for (int q = 0; q < 4; ++q) {
      float r = 1.f / (1.f + __expf(-(a0[q] + bg0)));
      u16 rv = f2bf(r * h_reg[q]);
      u32 lo = (u32)rv | ((u32)(u16)__shfl_xor((int)rv, 1) << 16);
      u32 hi = (u32)__shfl_xor((int)lo, 2);
      if ((l15 & 3) == 0) {
        st_u64_coh((u64*)(rhW + (lq4 + q) * 8), (u64)lo | ((u64)hi << 32));
      }
    }
    wave_arrive(fdom, ct, ++phase, lane);
    // ---- b1 window: z-gate full GEMM + cand x-part (ah still holds h) ----
    f32x4 a1 = {0.f, 0.f, 0.f, 0.f};
#pragma unroll
    for (int kb = 0; kb < 16; ++kb) {
      a1 = __builtin_amdgcn_mfma_f32_16x16x32_bf16(af[kb],
              ldsW(Wl, 16 + l15, kb * 32 + kq8), a1, 0, 0, 0);
    }
#pragma unroll
    for (int kb = 0; kb < 32; ++kb) {
      a1 = __builtin_amdgcn_mfma_f32_16x16x32_bf16(ah[kb],
              ldsW(Wl, 16 + l15, (kb + 16) * 32 + kq8), a1, 0, 0, 0);
    }
#pragma unroll
    for (int q = 0; q < 4; ++q)
      z_reg[q] = 1.f / (1.f + __expf(-(a1[q] + bg1)));
    f32x4 a2 = {0.f, 0.f, 0.f, 0.f};
#pragma unroll
    for (int kb = 0; kb < 16; ++kb) {
      a2 = __builtin_amdgcn_mfma_f32_16x16x32_bf16(af[kb],
              ldsW(Wl, 32 + l15, kb * 32 + kq8), a2, 0, 0, 0);
    }
    tok = wave_wait(fdom, phase, lane);

    // ---- Phase B (post-b1): cand h-part; h update; h exchange ----
    const u16* RpT = Rp + tok;
    LOAD32T(ah, RpT);
    WAIT_VM_ALL();
#pragma unroll
    for (int kb = 0; kb < 32; ++kb) {
      a2 = __builtin_amdgcn_mfma_f32_16x16x32_bf16(ah[kb],
              ldsW(Wl, 32 + l15, (kb + 16) * 32 + kq8), a2, 0, 0, 0);
    }
#pragma unroll
    for (int q = 0; q < 4; ++q) {
      int row = rbase + lq4 + q;
      float c = tanhf(a2[q] + bc0);
      float hn = z_reg[q] * h_reg[q] + (1.f - z_reg[q]) * c;
      float v = (t < len4[q]) ? hn : h_reg[q];
      h_reg[q] = v;
      u16 hv = f2bf(v);
      u32 lo = (u32)hv | ((u32)(u16)__shfl_xor((int)hv, 1) << 16);
      u32 hi = (u32)__shfl_xor((int)lo, 2);
      if ((l15 & 3) == 0) {
        st_u64_coh((u64*)(hW + (lq4 + q) * 8), (u64)lo | ((u64)hi << 32));
      }
      if (t == T_DIM - 1) {
        hF[(size_t)row * U_DIM + nc] = v;  // fp32 h for MLP (kernel boundary)
      }
    }
    wave_arrive(fdom, ct, ++phase, lane);
    // ---- b2 window: af(t+1) + gates-r x-part into carried a0 ----
    a0 = f32x4{0.f, 0.f, 0.f, 0.f};
    if (t + 1 < T_DIM) {
      const u16* Xt = X + ((size_t)(t + 1) * B_DIM + rbase + l15) * E_DIM + kq8;
#pragma unroll
      for (int kb = 0; kb < 16; ++kb) af[kb] = *(const bf16x8*)(Xt + kb * 32);
      WAIT_VM_ALL();
#pragma unroll
      for (int kb = 0; kb < 16; ++kb) {
        a0 = __builtin_amdgcn_mfma_f32_16x16x32_bf16(af[kb],
                ldsW(Wl, l15, kb * 32 + kq8), a0, 0, 0, 0);
      }
    }
    tok = wave_wait(fdom, phase, lane);
  }
}

__global__ __launch_bounds__(256) void mlp1_kernel(const float* __restrict__ h,
                                                   const float* __restrict__ W1,
                                                   const float* __restrict__ b1,
                                                   float* __restrict__ o1) {
  int m = blockIdx.x, tid = threadIdx.x;
  __shared__ float xs[1024];
  for (int k = tid; k < 1024; k += 256) xs[k] = h[(size_t)m * 1024 + k];
  __syncthreads();
  for (int n = tid; n < 512; n += 256) {
    float s = b1[n];
    for (int k = 0; k < 1024; ++k) s += xs[k] * W1[(size_t)k * 512 + n];
    o1[(size_t)m * 512 + n] = fmaxf(s, 0.f);
  }
}

__global__ __launch_bounds__(256) void mlp2_kernel(const float* __restrict__ x,
                                                   const float* __restrict__ W2,
                                                   const float* __restrict__ b2,
                                                   float* __restrict__ o2) {
  int m = blockIdx.x, tid = threadIdx.x;
  __shared__ float xs[512];
  for (int k = tid; k < 512; k += 256) xs[k] = x[(size_t)m * 512 + k];
  __syncthreads();
  int n = tid;
  float s = b2[n];
  for (int k = 0; k < 512; ++k) s += xs[k] * W2[(size_t)k * 256 + n];
  o2[(size_t)m * 256 + n] = fmaxf(s, 0.f);
}

__global__ __launch_bounds__(256) void mlp3_kernel(const float* __restrict__ x,
                                                   const float* __restrict__ W3,
                                                   const float* __restrict__ b3,
                                                   float* __restrict__ out) {
  int m = blockIdx.x, tid = threadIdx.x;
  float xk = x[(size_t)m * 256 + tid];
  float p0 = xk * W3[tid * 2 + 0];
  float p1 = xk * W3[tid * 2 + 1];
#pragma unroll
  for (int off = 32; off; off >>= 1) {
    p0 += __shfl_down(p0, off);
    p1 += __shfl_down(p1, off);
  }
  __shared__ float s0[4], s1[4];
  int wave = tid >> 6, lane = tid & 63;
  if (lane == 0) { s0[wave] = p0; s1[wave] = p1; }
  __syncthreads();
  if (tid == 0) {
    float l0 = s0[0] + s0[1] + s0[2] + s0[3] + b3[0];
    float l1 = s1[0] + s1[1] + s1[2] + s1[3] + b3[1];
    out[m * 2 + 0] = l0;
    out[m * 2 + 1] = l1;
    float mx = fmaxf(l0, l1);
    float e0 = __expf(l0 - mx), e1 = __expf(l1 - mx);
    float inv = 1.f / (e0 + e1);
    out[512 + m * 2 + 0] = e0 * inv;
    out[512 + m * 2 + 1] = e1 * inv;
  }
}

extern "C" void kernel_launch(void* const* d_in, const int* in_sizes, int n_in,
                              void* d_out, int out_size, void* d_ws, size_t ws_size,
                              hipStream_t stream) {
  (void)in_sizes; (void)n_in; (void)out_size; (void)ws_size;
  const int* inputs = (const int*)d_in[0];
  const int* lens = (const int*)d_in[1];
  const float* embedder = (const float*)d_in[2];
  const float* Wg = (const float*)d_in[3];
  const float* bg = (const float*)d_in[4];
  const float* Wc = (const float*)d_in[5];
  const float* bc = (const float*)d_in[6];
  const float* W1 = (const float*)d_in[7];
  const float* b1 = (const float*)d_in[8];
  const float* W2 = (const float*)d_in[9];
  const float* b2 = (const float*)d_in[10];
  const float* W3 = (const float*)d_in[11];
  const float* b3 = (const float*)d_in[12];
  float* out = (float*)d_out;

  char* ws = (char*)d_ws;
  size_t off = 0;
  u16* X = (u16*)(ws + off);       off += (size_t)T_DIM * B_DIM * E_DIM * 2;
  u16* WgT = (u16*)(ws + off);     off += (size_t)NG * K_DIM * 2;
  u16* WcT = (u16*)(ws + off);     off += (size_t)U_DIM * K_DIM * 2;
  float* hF = (float*)(ws + off);  off += (size_t)B_DIM * U_DIM * 4;
  u16* hB = (u16*)(ws + off);      off += (size_t)B_DIM * U_DIM * 2;
  u16* rhB = (u16*)(ws + off);     off += (size_t)B_DIM * U_DIM * 2;
  float* o1 = (float*)(ws + off);  off += (size_t)B_DIM * 512 * 4;
  float* o2 = (float*)(ws + off);  off += (size_t)B_DIM * 256 * 4;
  int* bar = (int*)(ws + off);     off += 65536;

  init_kernel<<<dim3(1024), dim3(256), 0, stream>>>(hF, hB, bar);
  wconv_kernel<<<dim3(24, 512), dim3(256), 0, stream>>>(Wg, WgT, NG);
  wconv_kernel<<<dim3(24, 256), dim3(256), 0, stream>>>(Wc, WcT, U_DIM);
  embed_kernel<<<dim3(T_DIM * B_DIM), dim3(128), 0, stream>>>(inputs, embedder, X);

  gru_loop<<<dim3(NWG), dim3(256), 0, stream>>>(X, WgT, WcT, bg, bc, hF, hB, rhB,
                                                lens, bar);

  mlp1_kernel<<<dim3(256), dim3(256), 0, stream>>>(hF, W1, b1, o1);
  mlp2_kernel<<<dim3(256), dim3(256), 0, stream>>>(o1, W2, b2, o2);
  mlp3_kernel<<<dim3(256), dim3(256), 0, stream>>>(o2, W3, b3, out);
}

// Round 19
// 6011.857 us; speedup vs baseline: 3.8534x; 1.0395x over previous
//
#include <hip/hip_runtime.h>

typedef unsigned short u16;
typedef unsigned int u32;
typedef unsigned long long u64;

using bf16x8 = __attribute__((ext_vector_type(8))) __bf16;
using f32x4  = __attribute__((ext_vector_type(4))) float;

#define T_DIM 512
#define B_DIM 256
#define E_DIM 512
#define U_DIM 1024
#define K_DIM 1536   /* E+U */
#define NG    2048   /* 2U */
#define NWG   256    /* persistent grid: 1 WG/CU on all 256 CUs */

__device__ __forceinline__ u16 f2bf(float f) {
  union { float f; u32 u; } v; v.f = f;
  return (u16)((v.u + 0x7fffu + ((v.u >> 16) & 1u)) >> 16);
}

// ---- device-coherent cross-WG traffic (r14-proven).
// h/rh transposed layout hT[row/16][k/8][row%16][8] (u16):
//   elem_addr = (row>>4)*16384 + (k>>3)*128 + (row&15)*8 + (k&7)
// One wave load instruction covers 1024 contiguous B = 8 lines.
#define WAIT_VM_ALL() do { asm volatile("s_waitcnt vmcnt(0)" ::: "memory"); \
                           __builtin_amdgcn_sched_barrier(0); } while (0)
// Staged drain: first 16 of 32 issued loads complete at vmcnt(16).
#define WAIT_VM_16() do { asm volatile("s_waitcnt vmcnt(16)" ::: "memory"); \
                          __builtin_amdgcn_sched_barrier(0); } while (0)

#define LD16T(dst, base, OFS) \
  asm volatile("global_load_dwordx4 %0, %1, off offset:" #OFS " sc0 sc1" \
               : "=&v"(dst) : "v"(base))

#define LOAD32T(arr, b) do { \
  const u16* _b0 = (b);           const u16* _b1 = (b) + 2048;  \
  const u16* _b2 = (b) + 4096;    const u16* _b3 = (b) + 6144;  \
  const u16* _b4 = (b) + 8192;    const u16* _b5 = (b) + 10240; \
  const u16* _b6 = (b) + 12288;   const u16* _b7 = (b) + 14336; \
  LD16T(arr[0],  _b0, 0); LD16T(arr[1],  _b0, 1024); \
  LD16T(arr[2],  _b0, 2048); LD16T(arr[3],  _b0, 3072); \
  LD16T(arr[4],  _b1, 0); LD16T(arr[5],  _b1, 1024); \
  LD16T(arr[6],  _b1, 2048); LD16T(arr[7],  _b1, 3072); \
  LD16T(arr[8],  _b2, 0); LD16T(arr[9],  _b2, 1024); \
  LD16T(arr[10], _b2, 2048); LD16T(arr[11], _b2, 3072); \
  LD16T(arr[12], _b3, 0); LD16T(arr[13], _b3, 1024); \
  LD16T(arr[14], _b3, 2048); LD16T(arr[15], _b3, 3072); \
  LD16T(arr[16], _b4, 0); LD16T(arr[17], _b4, 1024); \
  LD16T(arr[18], _b4, 2048); LD16T(arr[19], _b4, 3072); \
  LD16T(arr[20], _b5, 0); LD16T(arr[21], _b5, 1024); \
  LD16T(arr[22], _b5, 2048); LD16T(arr[23], _b5, 3072); \
  LD16T(arr[24], _b6, 0); LD16T(arr[25], _b6, 1024); \
  LD16T(arr[26], _b6, 2048); LD16T(arr[27], _b6, 3072); \
  LD16T(arr[28], _b7, 0); LD16T(arr[29], _b7, 1024); \
  LD16T(arr[30], _b7, 2048); LD16T(arr[31], _b7, 3072); \
} while (0)

// STORES: RETURNING atomic exchange — vmcnt ack == performed at the LLC.
__device__ __forceinline__ void st_u64_coh(u64* p, u64 v) {
  u64 r = __hip_atomic_exchange(p, v, __ATOMIC_RELAXED,
                                __HIP_MEMORY_SCOPE_AGENT);
  asm volatile("" :: "v"(r));  // keep returning form (no DCE to plain store)
}

__global__ __launch_bounds__(256) void init_kernel(float* hF, u16* hB, int* bar) {
  int i = blockIdx.x * 256 + threadIdx.x;
  hF[i] = 0.f;
  hB[i] = 0;
  if (i < 16384) bar[i] = 0;  // 16 domains x 1024 ints (64 flags x 8 ints ea)
}

// W [K_DIM][N] fp32 -> Wt [N][K_DIM] bf16
__global__ __launch_bounds__(256) void wconv_kernel(const float* __restrict__ W,
                                                    u16* __restrict__ Wt, int N) {
  int k = blockIdx.x * 64 + (threadIdx.x & 63);
  int n = blockIdx.y * 4 + (threadIdx.x >> 6);
  Wt[(size_t)n * K_DIM + k] = f2bf(W[(size_t)k * N + n]);
}

__global__ __launch_bounds__(128) void embed_kernel(const int* __restrict__ inp,
                                                    const float* __restrict__ emb,
                                                    u16* __restrict__ X) {
  int rb = blockIdx.x;
  int idx = inp[rb];
  int e = threadIdx.x * 4;
  float4 v = *(const float4*)&emb[(size_t)idx * E_DIM + e];
  ushort4 o;
  o.x = f2bf(v.x); o.y = f2bf(v.y); o.z = f2bf(v.z); o.w = f2bf(v.w);
  *(ushort4*)&X[(size_t)rb * E_DIM + e] = o;
}

// Swizzled LDS weight read: logical [48 cols][1536 k] bf16, row stride 3072 B.
__device__ __forceinline__ bf16x8 ldsW(const u16* Wl, int lc, int k) {
  int ofs = lc * 3072 + k * 2;
  ofs ^= ((lc & 7) << 4);
  return *(const bf16x8*)((const char*)Wl + ofs);
}

// WAVE-LOCAL rendezvous (r18-proven): sync domain = 16 rows (d = mq*4+wv).
// Arrival: wave drains its exchange-acks (vmcnt(0)), lane 0 posts flag[d][ct].
// Wait: 64 lanes BUSY-poll the domain's 64 flags (no s_sleep: at 1 wave/SIMD
// there is no co-tenant to yield to; sleep only added detection latency).
// Divergent-exit loop reconverges when all observed; per-lane data-dependent
// token (v>>30 == 0) gates the next loads' addresses — unhoistable.
__device__ __forceinline__ void wave_arrive(int* fdom, int ct, int phase,
                                            int lane) {
  WAIT_VM_ALL();
  if (lane == 0) {
    int r = __hip_atomic_exchange(&fdom[ct * 8], phase, __ATOMIC_RELAXED,
                                  __HIP_MEMORY_SCOPE_AGENT);
    asm volatile("" :: "v"(r));
  }
}
__device__ __forceinline__ int wave_wait(int* fdom, int phase, int lane) {
  int v;
  do {
    v = __hip_atomic_load(&fdom[(lane & 63) * 8], __ATOMIC_RELAXED,
                          __HIP_MEMORY_SCOPE_AGENT);
  } while (v < phase);
  return v >> 30;  // 0; per-lane dataflow token
}

// Persistent GRU loop. Grid: 256 WGs x 256 thr (VGPR ~204).
// WG = (col-tile ct in [0,64)) x (row-quarter mq in [0,4)); rows [mq*64,+64).
// ct owns gate cols [ct*16,+16) (r) + [1024+ct*16,+16) (z) + cand [ct*16,+16);
// z and fp32 h master live in registers. Schedule:
//   post-b2: a0 h-part (32 MFMA, 2-stage vmcnt) -> r -> rh exch -> arrive(b1)
//   b1 window: z full GEMM (48 MFMA) + cand x-part (16 MFMA)
//   post-b1: cand h-part (32 MFMA, 2-stage) -> h update -> h exch -> arrive(b2)
//   b2 window: af(t+1) load + gates-r x-part (16 MFMA, carried a0)
__global__ void __launch_bounds__(256, 1) gru_loop(
    const u16* __restrict__ X, const u16* __restrict__ WgT,
    const u16* __restrict__ WcT, const float* __restrict__ bg,
    const float* __restrict__ bc, float* __restrict__ hF,
    u16* __restrict__ hB, u16* __restrict__ rhB,
    const int* __restrict__ lens, int* bar) {
  __shared__ __align__(16) u16 Wl[48 * K_DIM];  // 147456 B
  const int tid = threadIdx.x;
  const int wgid = blockIdx.x;
  const int ct = wgid >> 2;
  const int mq = wgid & 3;

  // Stage weights once: 48 cols x 1536 k.
#pragma unroll 4
  for (int it = 0; it < 36; ++it) {
    int ci = it * 256 + tid;
    int lc = ci / 192;
    int k0 = (ci - lc * 192) * 8;
    const u16* src = (lc < 16)
        ? WgT + (size_t)(ct * 16 + lc) * K_DIM + k0
        : (lc < 32)
          ? WgT + (size_t)(1024 + ct * 16 + (lc - 16)) * K_DIM + k0
          : WcT + (size_t)(ct * 16 + (lc - 32)) * K_DIM + k0;
    uint4 v = *(const uint4*)src;
    int ofs = lc * 3072 + k0 * 2;
    ofs ^= ((lc & 7) << 4);
    *(uint4*)((char*)Wl + ofs) = v;
  }
  __syncthreads();  // one-time: weights visible to all 4 waves

  const int lane = tid & 63, wv = tid >> 6;
  const int l15 = lane & 15;
  const int kq8 = (lane >> 4) * 8;
  const int lq4 = (lane >> 4) * 4;
  const int rbase = mq * 64 + wv * 16;
  const int tbase = (rbase >> 4) * 16384 + (lane >> 4) * 128 + l15 * 8;
  const u16* Hp = hB + tbase;
  const u16* Rp = rhB + tbase;
  int* fdom = bar + (mq * 4 + wv) * 1024;  // this wave's 16-row sync domain

  int len4[4];
#pragma unroll
  for (int q = 0; q < 4; ++q) len4[q] = lens[rbase + lq4 + q];
  const int nc = ct * 16 + l15;
  const float bg0 = bg[nc];
  const float bg1 = bg[1024 + nc];
  const float bc0 = bc[nc];
  u16* rhW = rhB + (rbase >> 4) * 16384 + (nc >> 3) * 128 + (nc & 7);
  u16* hW  = hB  + (rbase >> 4) * 16384 + (nc >> 3) * 128 + (nc & 7);

  float h_reg[4] = {0.f, 0.f, 0.f, 0.f};
  float z_reg[4];

  bf16x8 af[16], ah[32];
  // Prologue: af(0) + gates-r x-part (carried a0).
  f32x4 a0 = {0.f, 0.f, 0.f, 0.f};
  {
    const u16* Xt = X + ((size_t)0 * B_DIM + rbase + l15) * E_DIM + kq8;
#pragma unroll
    for (int kb = 0; kb < 16; ++kb) af[kb] = *(const bf16x8*)(Xt + kb * 32);
    WAIT_VM_ALL();
#pragma unroll
    for (int kb = 0; kb < 16; ++kb) {
      a0 = __builtin_amdgcn_mfma_f32_16x16x32_bf16(af[kb],
              ldsW(Wl, l15, kb * 32 + kq8), a0, 0, 0, 0);
    }
  }

  int phase = 0;
  int tok = 0;  // t=0 h from init_kernel (kernel-boundary coherence)
  for (int t = 0; t < T_DIM; ++t) {
    // ---- Phase A (post-b2): r-gate h-part; 2-stage drain overlaps the
    // second half of the loads' RT under the first 16 MFMAs ----
    const u16* HpT = Hp + tok;
    LOAD32T(ah, HpT);
    WAIT_VM_16();
#pragma unroll
    for (int kb = 0; kb < 16; ++kb) {
      a0 = __builtin_amdgcn_mfma_f32_16x16x32_bf16(ah[kb],
              ldsW(Wl, l15, (kb + 16) * 32 + kq8), a0, 0, 0, 0);
    }
    WAIT_VM_ALL();
#pragma unroll
    for (int kb = 16; kb < 32; ++kb) {
      a0 = __builtin_amdgcn_mfma_f32_16x16x32_bf16(ah[kb],
              ldsW(Wl, l15, (kb + 16) * 32 + kq8), a0, 0, 0, 0);
    }
#pragma unroll
    for (int q = 0; q < 4; ++q) {
      float r = 1.f / (1.f + __expf(-(a0[q] + bg0)));
      u16 rv = f2bf(r * h_reg[q]);
      u32 lo = (u32)rv | ((u32)(u16)__shfl_xor((int)rv, 1) << 16);
      u32 hi = (u32)__shfl_xor((int)lo, 2);
      if ((l15 & 3) == 0) {
        st_u64_coh((u64*)(rhW + (lq4 + q) * 8), (u64)lo | ((u64)hi << 32));
      }
    }
    wave_arrive(fdom, ct, ++phase, lane);
    // ---- b1 window: z-gate full GEMM + cand x-part (ah still holds h) ----
    f32x4 a1 = {0.f, 0.f, 0.f, 0.f};
#pragma unroll
    for (int kb = 0; kb < 16; ++kb) {
      a1 = __builtin_amdgcn_mfma_f32_16x16x32_bf16(af[kb],
              ldsW(Wl, 16 + l15, kb * 32 + kq8), a1, 0, 0, 0);
    }
#pragma unroll
    for (int kb = 0; kb < 32; ++kb) {
      a1 = __builtin_amdgcn_mfma_f32_16x16x32_bf16(ah[kb],
              ldsW(Wl, 16 + l15, (kb + 16) * 32 + kq8), a1, 0, 0, 0);
    }
#pragma unroll
    for (int q = 0; q < 4; ++q)
      z_reg[q] = 1.f / (1.f + __expf(-(a1[q] + bg1)));
    f32x4 a2 = {0.f, 0.f, 0.f, 0.f};
#pragma unroll
    for (int kb = 0; kb < 16; ++kb) {
      a2 = __builtin_amdgcn_mfma_f32_16x16x32_bf16(af[kb],
              ldsW(Wl, 32 + l15, kb * 32 + kq8), a2, 0, 0, 0);
    }
    tok = wave_wait(fdom, phase, lane);

    // ---- Phase B (post-b1): cand h-part (2-stage); h update; h exchange ----
    const u16* RpT = Rp + tok;
    LOAD32T(ah, RpT);
    WAIT_VM_16();
#pragma unroll
    for (int kb = 0; kb < 16; ++kb) {
      a2 = __builtin_amdgcn_mfma_f32_16x16x32_bf16(ah[kb],
              ldsW(Wl, 32 + l15, (kb + 16) * 32 + kq8), a2, 0, 0, 0);
    }
    WAIT_VM_ALL();
#pragma unroll
    for (int kb = 16; kb < 32; ++kb) {
      a2 = __builtin_amdgcn_mfma_f32_16x16x32_bf16(ah[kb],
              ldsW(Wl, 32 + l15, (kb + 16) * 32 + kq8), a2, 0, 0, 0);
    }
#pragma unroll
    for (int q = 0; q < 4; ++q) {
      int row = rbase + lq4 + q;
      float c = tanhf(a2[q] + bc0);
      float hn = z_reg[q] * h_reg[q] + (1.f - z_reg[q]) * c;
      float v = (t < len4[q]) ? hn : h_reg[q];
      h_reg[q] = v;
      u16 hv = f2bf(v);
      u32 lo = (u32)hv | ((u32)(u16)__shfl_xor((int)hv, 1) << 16);
      u32 hi = (u32)__shfl_xor((int)lo, 2);
      if ((l15 & 3) == 0) {
        st_u64_coh((u64*)(hW + (lq4 + q) * 8), (u64)lo | ((u64)hi << 32));
      }
      if (t == T_DIM - 1) {
        hF[(size_t)row * U_DIM + nc] = v;  // fp32 h for MLP (kernel boundary)
      }
    }
    wave_arrive(fdom, ct, ++phase, lane);
    // ---- b2 window: af(t+1) + gates-r x-part into carried a0 ----
    a0 = f32x4{0.f, 0.f, 0.f, 0.f};
    if (t + 1 < T_DIM) {
      const u16* Xt = X + ((size_t)(t + 1) * B_DIM + rbase + l15) * E_DIM + kq8;
#pragma unroll
      for (int kb = 0; kb < 16; ++kb) af[kb] = *(const bf16x8*)(Xt + kb * 32);
      WAIT_VM_ALL();
#pragma unroll
      for (int kb = 0; kb < 16; ++kb) {
        a0 = __builtin_amdgcn_mfma_f32_16x16x32_bf16(af[kb],
                ldsW(Wl, l15, kb * 32 + kq8), a0, 0, 0, 0);
      }
    }
    tok = wave_wait(fdom, phase, lane);
  }
}

__global__ __launch_bounds__(256) void mlp1_kernel(const float* __restrict__ h,
                                                   const float* __restrict__ W1,
                                                   const float* __restrict__ b1,
                                                   float* __restrict__ o1) {
  int m = blockIdx.x, tid = threadIdx.x;
  __shared__ float xs[1024];
  for (int k = tid; k < 1024; k += 256) xs[k] = h[(size_t)m * 1024 + k];
  __syncthreads();
  for (int n = tid; n < 512; n += 256) {
    float s = b1[n];
    for (int k = 0; k < 1024; ++k) s += xs[k] * W1[(size_t)k * 512 + n];
    o1[(size_t)m * 512 + n] = fmaxf(s, 0.f);
  }
}

__global__ __launch_bounds__(256) void mlp2_kernel(const float* __restrict__ x,
                                                   const float* __restrict__ W2,
                                                   const float* __restrict__ b2,
                                                   float* __restrict__ o2) {
  int m = blockIdx.x, tid = threadIdx.x;
  __shared__ float xs[512];
  for (int k = tid; k < 512; k += 256) xs[k] = x[(size_t)m * 512 + k];
  __syncthreads();
  int n = tid;
  float s = b2[n];
  for (int k = 0; k < 512; ++k) s += xs[k] * W2[(size_t)k * 256 + n];
  o2[(size_t)m * 256 + n] = fmaxf(s, 0.f);
}

__global__ __launch_bounds__(256) void mlp3_kernel(const float* __restrict__ x,
                                                   const float* __restrict__ W3,
                                                   const float* __restrict__ b3,
                                                   float* __restrict__ out) {
  int m = blockIdx.x, tid = threadIdx.x;
  float xk = x[(size_t)m * 256 + tid];
  float p0 = xk * W3[tid * 2 + 0];
  float p1 = xk * W3[tid * 2 + 1];
#pragma unroll
  for (int off = 32; off; off >>= 1) {
    p0 += __shfl_down(p0, off);
    p1 += __shfl_down(p1, off);
  }
  __shared__ float s0[4], s1[4];
  int wave = tid >> 6, lane = tid & 63;
  if (lane == 0) { s0[wave] = p0; s1[wave] = p1; }
  __syncthreads();
  if (tid == 0) {
    float l0 = s0[0] + s0[1] + s0[2] + s0[3] + b3[0];
    float l1 = s1[0] + s1[1] + s1[2] + s1[3] + b3[1];
    out[m * 2 + 0] = l0;
    out[m * 2 + 1] = l1;
    float mx = fmaxf(l0, l1);
    float e0 = __expf(l0 - mx), e1 = __expf(l1 - mx);
    float inv = 1.f / (e0 + e1);
    out[512 + m * 2 + 0] = e0 * inv;
    out[512 + m * 2 + 1] = e1 * inv;
  }
}

extern "C" void kernel_launch(void* const* d_in, const int* in_sizes, int n_in,
                              void* d_out, int out_size, void* d_ws, size_t ws_size,
                              hipStream_t stream) {
  (void)in_sizes; (void)n_in; (void)out_size; (void)ws_size;
  const int* inputs = (const int*)d_in[0];
  const int* lens = (const int*)d_in[1];
  const float* embedder = (const float*)d_in[2];
  const float* Wg = (const float*)d_in[3];
  const float* bg = (const float*)d_in[4];
  const float* Wc = (const float*)d_in[5];
  const float* bc = (const float*)d_in[6];
  const float* W1 = (const float*)d_in[7];
  const float* b1 = (const float*)d_in[8];
  const float* W2 = (const float*)d_in[9];
  const float* b2 = (const float*)d_in[10];
  const float* W3 = (const float*)d_in[11];
  const float* b3 = (const float*)d_in[12];
  float* out = (float*)d_out;

  char* ws = (char*)d_ws;
  size_t off = 0;
  u16* X = (u16*)(ws + off);       off += (size_t)T_DIM * B_DIM * E_DIM * 2;
  u16* WgT = (u16*)(ws + off);     off += (size_t)NG * K_DIM * 2;
  u16* WcT = (u16*)(ws + off);     off += (size_t)U_DIM * K_DIM * 2;
  float* hF = (float*)(ws + off);  off += (size_t)B_DIM * U_DIM * 4;
  u16* hB = (u16*)(ws + off);      off += (size_t)B_DIM * U_DIM * 2;
  u16* rhB = (u16*)(ws + off);     off += (size_t)B_DIM * U_DIM * 2;
  float* o1 = (float*)(ws + off);  off += (size_t)B_DIM * 512 * 4;
  float* o2 = (float*)(ws + off);  off += (size_t)B_DIM * 256 * 4;
  int* bar = (int*)(ws + off);     off += 65536;

  init_kernel<<<dim3(1024), dim3(256), 0, stream>>>(hF, hB, bar);
  wconv_kernel<<<dim3(24, 512), dim3(256), 0, stream>>>(Wg, WgT, NG);
  wconv_kernel<<<dim3(24, 256), dim3(256), 0, stream>>>(Wc, WcT, U_DIM);
  embed_kernel<<<dim3(T_DIM * B_DIM), dim3(128), 0, stream>>>(inputs, embedder, X);

  gru_loop<<<dim3(NWG), dim3(256), 0, stream>>>(X, WgT, WcT, bg, bc, hF, hB, rhB,
                                                lens, bar);

  mlp1_kernel<<<dim3(256), dim3(256), 0, stream>>>(hF, W1, b1, o1);
  mlp2_kernel<<<dim3(256), dim3(256), 0, stream>>>(o1, W2, b2, o2);
  mlp3_kernel<<<dim3(256), dim3(256), 0, stream>>>(o2, W3, b3, out);
}